// Round 7
// baseline (273.172 us; speedup 1.0000x reference)
//
#include <hip/hip_runtime.h>

#define NUM_CLASSES 32
#define NBINS (NUM_CLASSES * NUM_CLASSES)
#define B_CONST 4
#define GRID_X 1024

typedef int v4i __attribute__((ext_vector_type(4)));  // plain vector: nontemporal-load OK

// ws layout: [B*96 uint counters][1 uint completion counter]
//   per batch: [hist_in(32), hist_tg(32), inter(32)]
__global__ void __launch_bounds__(256, 8)
dice_fused_kernel(const int* __restrict__ in,
                  const int* __restrict__ tg,
                  const float* __restrict__ smooth_p,
                  unsigned int* __restrict__ ws,
                  float* __restrict__ out,
                  long long nPerB, unsigned int gridTotal) {
    const int b = blockIdx.y;
    __shared__ unsigned int h[NBINS];
    __shared__ bool isLast;
    for (int i = threadIdx.x; i < NBINS; i += blockDim.x) h[i] = 0u;
    __syncthreads();

    const long long base = (long long)b * nPerB;
    const v4i* in4 = (const v4i*)(in + base);
    const v4i* tg4 = (const v4i*)(tg + base);
    const long long n4 = nPerB >> 2;
    const long long stride = (long long)gridDim.x * blockDim.x;

#define ATOM4(a, t)                                      \
    atomicAdd(&h[((a.x & 31) << 5) | (t.x & 31)], 1u);   \
    atomicAdd(&h[((a.y & 31) << 5) | (t.y & 31)], 1u);   \
    atomicAdd(&h[((a.z & 31) << 5) | (t.z & 31)], 1u);   \
    atomicAdd(&h[((a.w & 31) << 5) | (t.w & 31)], 1u)

    // Cache-policy split: `in` cacheable (L3-resident across replays), `tg`
    // nontemporal. Depth-2 software pipeline: 4 loads in flight during atomics.
    long long i0 = (long long)blockIdx.x * blockDim.x + threadIdx.x;
    const bool h0 = (i0 < n4);
    const bool h1 = (i0 + stride < n4);
    v4i a0, t0, a1, t1;
    if (h0) {
        a0 = in4[i0];
        t0 = __builtin_nontemporal_load(&tg4[i0]);
    }
    if (h1) {
        a1 = in4[i0 + stride];
        t1 = __builtin_nontemporal_load(&tg4[i0 + stride]);
    }
    #pragma unroll 2
    for (long long j = i0 + 2 * stride; j < n4; j += stride) {
        v4i na = in4[j];
        v4i nt = __builtin_nontemporal_load(&tg4[j]);
        ATOM4(a0, t0);
        a0 = a1; t0 = t1;
        a1 = na; t1 = nt;
    }
    if (h0) { ATOM4(a0, t0); }
    if (h1) { ATOM4(a1, t1); }
#undef ATOM4
    __syncthreads();

    // Reduce 2-D histogram -> 96 per-batch global counters.
    unsigned int* wsb = ws + b * 96;
    const int t = threadIdx.x;
    if (t < 32) {                       // hist_in[c] = sum_k h[c][k]
        unsigned int s = 0;
        #pragma unroll
        for (int k = 0; k < 32; ++k) s += h[(t << 5) | k];
        atomicAdd(&wsb[t], s);
    } else if (t < 64) {                // hist_tg[c] = sum_k h[k][c]
        const int c = t - 32;
        unsigned int s = 0;
        #pragma unroll
        for (int k = 0; k < 32; ++k) s += h[(k << 5) | c];
        atomicAdd(&wsb[32 + c], s);
    } else if (t < 96) {                // inter[c] = h[c][c]
        const int c = t - 64;
        atomicAdd(&wsb[64 + c], h[(c << 5) | c]);
    }
    __syncthreads();   // this block's 96 adds issued

    // Completion counter: last block computes the dice loss inline.
    if (threadIdx.x == 0) {
        __threadfence();  // release this block's counter adds
        isLast = (atomicAdd(&ws[B_CONST * 96], 1u) == gridTotal - 1u);
    }
    __syncthreads();

    if (isLast && threadIdx.x < 64) {
        __threadfence();  // acquire all blocks' adds
        const double s = (double)smooth_p[0];
        double acc = 0.0;
        for (int idx = threadIdx.x; idx < B_CONST * 32; idx += 64) {
            const int bb = idx >> 5, c = idx & 31;
            const unsigned int* p = ws + bb * 96;
            const double inter = (double)__hip_atomic_load(
                &p[64 + c], __ATOMIC_RELAXED, __HIP_MEMORY_SCOPE_AGENT);
            const double total = (double)__hip_atomic_load(
                &p[c], __ATOMIC_RELAXED, __HIP_MEMORY_SCOPE_AGENT)
                               + (double)__hip_atomic_load(
                &p[32 + c], __ATOMIC_RELAXED, __HIP_MEMORY_SCOPE_AGENT);
            acc += 1.0 - (2.0 * inter + s) / (total + s);
        }
        #pragma unroll
        for (int off = 32; off > 0; off >>= 1) acc += __shfl_down(acc, off);
        if (threadIdx.x == 0) out[0] = (float)(acc / (double)B_CONST);
    }
}

extern "C" void kernel_launch(void* const* d_in, const int* in_sizes, int n_in,
                              void* d_out, int out_size, void* d_ws, size_t ws_size,
                              hipStream_t stream) {
    const int* in = (const int*)d_in[0];
    const int* tg = (const int*)d_in[1];
    const float* smooth = (const float*)d_in[2];
    float* out = (float*)d_out;

    const long long total = (long long)in_sizes[0];
    const long long nPerB = total / B_CONST;

    // Zero counters + completion counter every call (harness poisons ws once).
    (void)hipMemsetAsync(d_ws, 0, (size_t)(B_CONST * 96 + 1) * sizeof(unsigned int), stream);

    dim3 grid(GRID_X, B_CONST);
    dice_fused_kernel<<<grid, dim3(256), 0, stream>>>(
        in, tg, smooth, (unsigned int*)d_ws, out, nPerB,
        (unsigned int)(GRID_X * B_CONST));
}

// Round 8
// 92.421 us; speedup vs baseline: 2.9557x; 2.9557x over previous
//
#include <hip/hip_runtime.h>

#define NUM_CLASSES 32
#define NBINS (NUM_CLASSES * NUM_CLASSES)

typedef int v4i __attribute__((ext_vector_type(4)));  // plain vector: nontemporal-load OK

// Per-batch workspace layout: [hist_in(32), hist_tg(32), inter(32)] uint32
__global__ void __launch_bounds__(256, 8)
dice_hist_kernel(const int* __restrict__ in,
                 const int* __restrict__ tg,
                 unsigned int* __restrict__ ws,
                 long long nPerB) {
    const int b = blockIdx.y;
    __shared__ unsigned int h[NBINS];
    for (int i = threadIdx.x; i < NBINS; i += blockDim.x) h[i] = 0u;
    __syncthreads();

    const long long base = (long long)b * nPerB;
    const v4i* in4 = (const v4i*)(in + base);
    const v4i* tg4 = (const v4i*)(tg + base);
    const long long n4 = nPerB >> 2;
    const long long stride = (long long)gridDim.x * blockDim.x;

#define ATOM4(a, t)                                      \
    atomicAdd(&h[((a.x & 31) << 5) | (t.x & 31)], 1u);   \
    atomicAdd(&h[((a.y & 31) << 5) | (t.y & 31)], 1u);   \
    atomicAdd(&h[((a.z & 31) << 5) | (t.z & 31)], 1u);   \
    atomicAdd(&h[((a.w & 31) << 5) | (t.w & 31)], 1u)

    // Cache-policy split: `in` is cacheable (Infinity Cache retains ~all 268MB
    // across replays); `tg` is nontemporal (streams from HBM, doesn't evict in).
    // Depth-2 software pipeline: 4 loads always in flight during atomics.
    // NOTE (R4/R7 lesson): do NOT fuse the finisher into this kernel — the
    // epilogue's register demands make the allocator sink these pipeline
    // loads (VGPR 40->24) and throughput collapses 6.1 -> 0.8 TB/s.
    long long i0 = (long long)blockIdx.x * blockDim.x + threadIdx.x;
    const bool h0 = (i0 < n4);
    const bool h1 = (i0 + stride < n4);
    v4i a0, t0, a1, t1;
    if (h0) {
        a0 = in4[i0];
        t0 = __builtin_nontemporal_load(&tg4[i0]);
    }
    if (h1) {
        a1 = in4[i0 + stride];
        t1 = __builtin_nontemporal_load(&tg4[i0 + stride]);
    }
    #pragma unroll 2
    for (long long j = i0 + 2 * stride; j < n4; j += stride) {
        v4i na = in4[j];
        v4i nt = __builtin_nontemporal_load(&tg4[j]);
        ATOM4(a0, t0);
        a0 = a1; t0 = t1;
        a1 = na; t1 = nt;
    }
    if (h0) { ATOM4(a0, t0); }
    if (h1) { ATOM4(a1, t1); }
#undef ATOM4
    __syncthreads();

    // Reduce 2-D histogram -> 96 per-batch counters.
    unsigned int* wsb = ws + b * 96;
    const int t = threadIdx.x;
    if (t < 32) {                       // hist_in[c] = sum_k h[c][k]
        unsigned int s = 0;
        #pragma unroll
        for (int k = 0; k < 32; ++k) s += h[(t << 5) | k];
        atomicAdd(&wsb[t], s);
    } else if (t < 64) {                // hist_tg[c] = sum_k h[k][c]
        const int c = t - 32;
        unsigned int s = 0;
        #pragma unroll
        for (int k = 0; k < 32; ++k) s += h[(k << 5) | c];
        atomicAdd(&wsb[32 + c], s);
    } else if (t < 96) {                // inter[c] = h[c][c]
        const int c = t - 64;
        atomicAdd(&wsb[64 + c], h[(c << 5) | c]);
    }
}

__global__ void dice_final_kernel(const unsigned int* __restrict__ ws,
                                  const float* __restrict__ smooth_p,
                                  float* __restrict__ out, int B) {
    const double s = (double)smooth_p[0];
    const int lane = threadIdx.x;  // 64 threads, 1 block, 1 wave
    double acc = 0.0;
    for (int idx = lane; idx < B * 32; idx += 64) {
        const int b = idx >> 5, c = idx & 31;
        const unsigned int* wsb = ws + b * 96;
        const double inter = (double)wsb[64 + c];
        const double total = (double)wsb[c] + (double)wsb[32 + c];
        acc += 1.0 - (2.0 * inter + s) / (total + s);
    }
    #pragma unroll
    for (int off = 32; off > 0; off >>= 1) acc += __shfl_down(acc, off);
    if (lane == 0) out[0] = (float)(acc / (double)B);
}

extern "C" void kernel_launch(void* const* d_in, const int* in_sizes, int n_in,
                              void* d_out, int out_size, void* d_ws, size_t ws_size,
                              hipStream_t stream) {
    const int* in = (const int*)d_in[0];
    const int* tg = (const int*)d_in[1];
    const float* smooth = (const float*)d_in[2];
    float* out = (float*)d_out;

    const int B = 4;
    const long long total = (long long)in_sizes[0];
    const long long nPerB = total / B;

    // Zero the 96-per-batch counters every call (harness poisons ws once).
    (void)hipMemsetAsync(d_ws, 0, (size_t)(B * 96) * sizeof(unsigned int), stream);

    dim3 grid(512, B);
    dice_hist_kernel<<<grid, dim3(256), 0, stream>>>(in, tg, (unsigned int*)d_ws, nPerB);
    dice_final_kernel<<<1, 64, 0, stream>>>((const unsigned int*)d_ws, smooth, out, B);
}